// Round 20
// baseline (140.475 us; speedup 1.0000x reference)
//
#include <hip/hip_runtime.h>
#include <hip/hip_bf16.h>

// RGCN layer, MI355X (gfx950).
// R20 = R19 + sparse-row store elision in gemm. P(X row (src,typ) unused) = e^-1.25
// = 28.7% (E=1M uniform over 800K pairs); each row is a private 128B 2-line region,
// so gating stores on a usage mask cuts gemm write traffic 100 -> ~71MB (~-9us at the
// measured ~3.2TB/s write wall). Mask (100KB, bit = src*16+typ) is built by k_hist
// (global atomicOr) -- which forces UNFUSING hist from gemm (in-kernel there is no
// hist->gemm ordering; a race could skip used rows). Mask zeroed in k_wt (earlier
// dispatch, no extra launch). Gather only reads rows with a real edge -> always stored.
//  K0 k_wt (+mask zero) | K1 k_hist (+mask OR) | K2 k_gemm (masked stores) |
//  K3 k_scan_a | K4 k_scan_b | K5 k_scatter | K6 k_sortgather (R19 fused gather).
//
// ws: X 102.4MB | Wt 128KB | rec 8MB | cntT 800KB | offsT 800KB | bsum | bsum2 | mask 100KB

#define NN 50000
#define EE 1000000
#define RR 16
#define NBLK 256            // binning blocks (hist/scatter)
#define EPB 3907            // ceil(EE/NBLK)
#define BSH 6               // 64 nodes per bucket
#define NBUK 782            // ceil(NN/64)
#define NS (NBUK * NBLK)    // 200192
#define SCAP 2048           // bucket LDS record capacity (mean 1279, +21 sigma)
#define NMW 25008           // mask words (ceil(800000/32)=25000, padded to 16*1563)

typedef __attribute__((ext_vector_type(8))) short short8;
typedef __attribute__((ext_vector_type(4))) float f32x4;

static __device__ inline unsigned short f2bf(float f) {
  union { __hip_bfloat16 h; unsigned short u; } cv;
  cv.h = __float2bfloat16(f);
  return cv.u;
}
static __device__ inline float bf2f(unsigned short u) {
  union { unsigned i; float f; } cv;
  cv.i = ((unsigned)u) << 16;
  return cv.f;
}

// ---------------- K0: W transpose to bf16 + mask zero ----------------
__global__ __launch_bounds__(256) void k_wt(const float* __restrict__ W,
                                            unsigned short* __restrict__ Wt,
                                            unsigned* __restrict__ mask) {
  __shared__ __align__(16) unsigned short Wl[64][72];
  const int r = blockIdx.x, tid = threadIdx.x;
  // zero usage mask: 25008 words over 16 blocks
  for (int i = tid; i < NMW / RR; i += 256) mask[r * (NMW / RR) + i] = 0;
  for (int i = tid; i < 4096; i += 256) Wl[i & 63][i >> 6] = f2bf(W[(r << 12) + i]);
  __syncthreads();
  const int o = tid >> 2, kc = (tid & 3) << 4;
  const short8 v0 = *reinterpret_cast<const short8*>(&Wl[o][kc]);
  const short8 v1 = *reinterpret_cast<const short8*>(&Wl[o][kc + 8]);
  unsigned short* dst = Wt + (r << 12) + (o << 6) + kc;
  *reinterpret_cast<short8*>(dst) = v0;
  *reinterpret_cast<short8*>(dst + 8) = v1;
}

// ---------------- K1: edge histogram + (src,typ) usage mask ----------------
__global__ __launch_bounds__(256) void k_hist(const int* __restrict__ esrc,
                                              const int* __restrict__ edst,
                                              const int* __restrict__ etyp,
                                              int* __restrict__ cntT,
                                              unsigned* __restrict__ mask) {
  __shared__ int cnt[NBUK];
  const int bl = blockIdx.x, tid = threadIdx.x;
  for (int i = tid; i < NBUK; i += 256) cnt[i] = 0;
  __syncthreads();
  const int e0 = bl * EPB, e1 = min(EE, e0 + EPB);
  for (int e = e0 + tid; e < e1; e += 256) {
    atomicAdd(&cnt[edst[e] >> BSH], 1);
    const unsigned bit = ((unsigned)esrc[e] << 4) | (unsigned)etyp[e];
    atomicOr(&mask[bit >> 5], 1u << (bit & 31));
  }
  __syncthreads();
  for (int i = tid; i < NBUK; i += 256) cntT[i * NBLK + bl] = cnt[i];
}

// ---------------- K2: dense transform, mask-gated stores ----------------
// R11 config: grid (782,4), 256 thr, LDS Wt. Store of X row (node, r) elided when
// mask bit node*16+r is clear (row never read by gather).
__global__ __launch_bounds__(256) void k_gemm(const float* __restrict__ nf,
                                              const unsigned short* __restrict__ Wt,
                                              const unsigned* __restrict__ mask,
                                              unsigned short* __restrict__ X) {
  __shared__ __align__(16) unsigned short Wl[4][64][72];  // 36,864 B
  const int tid = threadIdx.x;
  const int lane = tid & 63, wv = tid >> 6;
  const int lr = lane & 15, lg = lane >> 4;
  const int node = (blockIdx.x << 6) + (wv << 4) + lr;
  const int r0 = blockIdx.y << 2;
  #pragma unroll
  for (int rr = 0; rr < 4; ++rr) {
    const unsigned short* src = Wt + (((size_t)(r0 + rr)) << 12) + (tid << 4);
    const short8 v0 = *reinterpret_cast<const short8*>(src);
    const short8 v1 = *reinterpret_cast<const short8*>(src + 8);
    unsigned short* dst = &Wl[rr][tid >> 2][(tid & 3) << 4];
    *reinterpret_cast<short8*>(dst) = v0;
    *reinterpret_cast<short8*>(dst + 8) = v1;
  }
  short8 bf0, bf1;
  unsigned m16 = 0;
  if (node < NN) {
    m16 = (mask[node >> 1] >> ((node & 1) << 4)) & 0xffffu;  // 16 relation bits
    const float* ap = nf + (size_t)node * 64 + lg * 8;
    float4 v0 = *reinterpret_cast<const float4*>(ap);
    float4 v1 = *reinterpret_cast<const float4*>(ap + 4);
    float4 v2 = *reinterpret_cast<const float4*>(ap + 32);
    float4 v3 = *reinterpret_cast<const float4*>(ap + 36);
    bf0 = short8{(short)f2bf(v0.x), (short)f2bf(v0.y), (short)f2bf(v0.z), (short)f2bf(v0.w),
                 (short)f2bf(v1.x), (short)f2bf(v1.y), (short)f2bf(v1.z), (short)f2bf(v1.w)};
    bf1 = short8{(short)f2bf(v2.x), (short)f2bf(v2.y), (short)f2bf(v2.z), (short)f2bf(v2.w),
                 (short)f2bf(v3.x), (short)f2bf(v3.y), (short)f2bf(v3.z), (short)f2bf(v3.w)};
  } else {
    bf0 = short8{0, 0, 0, 0, 0, 0, 0, 0};
    bf1 = bf0;
  }
  __syncthreads();
  #pragma unroll
  for (int rr = 0; rr < 4; ++rr) {
    const int r = r0 + rr;
    short8 a[8];
    #pragma unroll
    for (int c = 0; c < 4; ++c) {
      a[2 * c] = *reinterpret_cast<const short8*>(&Wl[rr][(c << 4) + lr][lg << 3]);
      a[2 * c + 1] = *reinterpret_cast<const short8*>(&Wl[rr][(c << 4) + lr][32 + (lg << 3)]);
    }
    f32x4 acc[4];
    #pragma unroll
    for (int c = 0; c < 4; ++c) {
      acc[c] = f32x4{0.f, 0.f, 0.f, 0.f};
      acc[c] = __builtin_amdgcn_mfma_f32_16x16x32_bf16(a[2 * c], bf0, acc[c], 0, 0, 0);
      acc[c] = __builtin_amdgcn_mfma_f32_16x16x32_bf16(a[2 * c + 1], bf1, acc[c], 0, 0, 0);
    }
    if (node < NN && ((m16 >> r) & 1u)) {
      #pragma unroll
      for (int c = 0; c < 4; ++c) {
        uint2 p;
        p.x = (unsigned)f2bf(acc[c][0]) | ((unsigned)f2bf(acc[c][1]) << 16);
        p.y = (unsigned)f2bf(acc[c][2]) | ((unsigned)f2bf(acc[c][3]) << 16);
        *reinterpret_cast<uint2*>(&X[((size_t)r * NN + node) * 64 + (c << 4) + (lg << 2)]) = p;
      }
    }
  }
}

// ---------------- K3: per-bucket scan of per-block counts ----------------
__global__ __launch_bounds__(256) void k_scan_a(const int* __restrict__ cntT,
                                                int* __restrict__ offsT,
                                                int* __restrict__ bsum) {
  __shared__ int s[256];
  const int t = threadIdx.x;
  const int i = blockIdx.x * 256 + t;
  const int v = cntT[i];
  s[t] = v;
  __syncthreads();
  #pragma unroll
  for (int off = 1; off < 256; off <<= 1) {
    const int x = (t >= off) ? s[t - off] : 0;
    __syncthreads();
    s[t] += x;
    __syncthreads();
  }
  offsT[i] = s[t] - v;
  if (t == 255) bsum[blockIdx.x] = s[255];
}

// ---------------- K4: scan bucket totals -> global bucket starts ----------------
__global__ __launch_bounds__(1024) void k_scan_b(const int* __restrict__ bsum,
                                                 int* __restrict__ bsum2) {
  __shared__ int s[1024];
  const int t = threadIdx.x;
  const int v = (t < NBUK) ? bsum[t] : 0;
  s[t] = v;
  __syncthreads();
  #pragma unroll
  for (int off = 1; off < 1024; off <<= 1) {
    const int x = (t >= off) ? s[t - off] : 0;
    __syncthreads();
    s[t] += x;
    __syncthreads();
  }
  if (t < NBUK) bsum2[t] = s[t] - v;
  if (t == NBUK) bsum2[NBUK] = EE;
}

// ---------------- K5: private counting-sort scatter ----------------
__global__ __launch_bounds__(256) void k_scatter(const int* __restrict__ esrc,
                                                 const int* __restrict__ edst,
                                                 const int* __restrict__ etyp,
                                                 const float* __restrict__ enorm,
                                                 const int* __restrict__ offsT,
                                                 const int* __restrict__ bsum2,
                                                 uint2* __restrict__ rec) {
  __shared__ int cur[NBUK];
  const int bl = blockIdx.x, tid = threadIdx.x;
  for (int i = tid; i < NBUK; i += 256) cur[i] = offsT[i * NBLK + bl] + bsum2[i];
  __syncthreads();
  const int e0 = bl * EPB, e1 = min(EE, e0 + EPB);
  for (int e = e0 + tid; e < e1; e += 256) {
    const int d = edst[e];
    const int pos = atomicAdd(&cur[d >> BSH], 1);
    // pack: (typ*NN+src)<<6 | dstlow  (r.x>>6 == X row id, typ-major layout)
    rec[pos] = make_uint2(((unsigned)(etyp[e] * NN + esrc[e]) << 6) | (unsigned)(d & 63),
                          __float_as_uint(enorm[e]));
  }
}

// ---------------- K6: fused in-LDS node sort + gather + bias + relu ----------------
__global__ __launch_bounds__(1024) void k_sortgather(const int* __restrict__ bsum2,
                                                     const uint2* __restrict__ rec,
                                                     const unsigned short* __restrict__ X,
                                                     const float* __restrict__ bias,
                                                     float* __restrict__ out) {
  __shared__ uint2 sbuf[SCAP];   // 16 KB raw
  __shared__ uint2 sbuf2[SCAP];  // 16 KB node-sorted
  __shared__ int cnt[64], cur[64], nstart[65];
  const int bu = blockIdx.x, tid = threadIdx.x;
  const int s = bsum2[bu];
  const int e = bsum2[bu + 1];
  const int n = e - s;
  const int lane = tid & 63, wv = tid >> 6;
  const int quarter = lane >> 4, d4 = lane & 15;
  if (tid < 64) cnt[tid] = 0;
  __syncthreads();
  const bool sorted = (n <= SCAP);
  if (sorted) {
    for (int i = tid; i < n; i += 1024) {
      const uint2 r = rec[s + i];
      sbuf[i] = r;
      atomicAdd(&cnt[r.x & 63u], 1);  // native ds_add_u32
    }
    __syncthreads();
    if (tid < 64) {  // wave-0 shfl exclusive scan of 64 bins
      const int v = cnt[tid];
      int x = v;
      #pragma unroll
      for (int off = 1; off < 64; off <<= 1) {
        const int t = __shfl_up(x, off, 64);
        if (tid >= off) x += t;
      }
      cur[tid] = x - v;
      nstart[tid] = x - v;
      if (tid == 63) nstart[64] = n;
    }
    __syncthreads();
    for (int i = tid; i < n; i += 1024) {
      const uint2 r = sbuf[i];
      const int pos = atomicAdd(&cur[r.x & 63u], 1);
      sbuf2[pos] = r;
    }
    __syncthreads();
  }
  // gather: wave wv owns local nodes wv*4 .. wv*4+3 (no barriers below)
  #pragma unroll
  for (int k = 0; k < 4; ++k) {
    const int nl = (wv << 2) + k;
    const int w = (bu << BSH) + nl;
    float4 acc = {0.f, 0.f, 0.f, 0.f};
    if (sorted) {
      const int jb = nstart[nl], je = nstart[nl + 1];
      for (int base = jb; base < je; base += 64) {
        const int deg = min(64, je - base);
        unsigned rxs = 0;
        float rns = 0.f;
        if (lane < deg) {
          const uint2 r = sbuf2[base + lane];
          rxs = r.x >> 6;
          rns = __uint_as_float(r.y);
        }
        int u = 0;
        for (; u + 16 <= deg; u += 16) {  // 16 edges per body, 4 independent X loads
          unsigned row[4];
          float nm[4];
          uint2 xv[4];
          #pragma unroll
          for (int q = 0; q < 4; ++q) {
            const int i = u + 4 * q + quarter;
            row[q] = (unsigned)__shfl((int)rxs, i, 64);
            nm[q] = __shfl(rns, i, 64);
          }
          #pragma unroll
          for (int q = 0; q < 4; ++q)
            xv[q] = *reinterpret_cast<const uint2*>(X + (size_t)row[q] * 64 + (d4 << 2));
          #pragma unroll
          for (int q = 0; q < 4; ++q) {
            acc.x = fmaf(nm[q], bf2f((unsigned short)(xv[q].x & 0xffffu)), acc.x);
            acc.y = fmaf(nm[q], bf2f((unsigned short)(xv[q].x >> 16)), acc.y);
            acc.z = fmaf(nm[q], bf2f((unsigned short)(xv[q].y & 0xffffu)), acc.z);
            acc.w = fmaf(nm[q], bf2f((unsigned short)(xv[q].y >> 16)), acc.w);
          }
        }
        for (; u + 8 <= deg; u += 8) {
          const int i0 = u + quarter, i1 = u + 4 + quarter;
          const unsigned row0 = (unsigned)__shfl((int)rxs, i0, 64);
          const float n0 = __shfl(rns, i0, 64);
          const unsigned row1 = (unsigned)__shfl((int)rxs, i1, 64);
          const float n1 = __shfl(rns, i1, 64);
          const uint2 x0 = *reinterpret_cast<const uint2*>(X + (size_t)row0 * 64 + (d4 << 2));
          const uint2 x1 = *reinterpret_cast<const uint2*>(X + (size_t)row1 * 64 + (d4 << 2));
          acc.x = fmaf(n0, bf2f((unsigned short)(x0.x & 0xffffu)), acc.x);
          acc.y = fmaf(n0, bf2f((unsigned short)(x0.x >> 16)), acc.y);
          acc.z = fmaf(n0, bf2f((unsigned short)(x0.y & 0xffffu)), acc.z);
          acc.w = fmaf(n0, bf2f((unsigned short)(x0.y >> 16)), acc.w);
          acc.x = fmaf(n1, bf2f((unsigned short)(x1.x & 0xffffu)), acc.x);
          acc.y = fmaf(n1, bf2f((unsigned short)(x1.x >> 16)), acc.y);
          acc.z = fmaf(n1, bf2f((unsigned short)(x1.y & 0xffffu)), acc.z);
          acc.w = fmaf(n1, bf2f((unsigned short)(x1.y >> 16)), acc.w);
        }
        for (; u < deg; u += 4) {
          const int i = u + quarter;
          const int ic = min(i, deg - 1);
          const unsigned row = (unsigned)__shfl((int)rxs, ic, 64);
          float nm = __shfl(rns, ic, 64);
          nm = (i < deg) ? nm : 0.f;
          const uint2 x = *reinterpret_cast<const uint2*>(X + (size_t)row * 64 + (d4 << 2));
          acc.x = fmaf(nm, bf2f((unsigned short)(x.x & 0xffffu)), acc.x);
          acc.y = fmaf(nm, bf2f((unsigned short)(x.x >> 16)), acc.y);
          acc.z = fmaf(nm, bf2f((unsigned short)(x.y & 0xffffu)), acc.z);
          acc.w = fmaf(nm, bf2f((unsigned short)(x.y >> 16)), acc.w);
        }
      }
    } else if (quarter == 0) {
      // ~impossible oversized bucket: filter-scan global rec
      const unsigned dl = (unsigned)nl;
      for (int j = s; j < e; ++j) {
        const uint2 r = rec[j];
        if ((r.x & 63u) == dl) {
          const float nm = __uint_as_float(r.y);
          const uint2 x =
              *reinterpret_cast<const uint2*>(X + (size_t)(r.x >> 6) * 64 + (d4 << 2));
          acc.x = fmaf(nm, bf2f((unsigned short)(x.x & 0xffffu)), acc.x);
          acc.y = fmaf(nm, bf2f((unsigned short)(x.x >> 16)), acc.y);
          acc.z = fmaf(nm, bf2f((unsigned short)(x.y & 0xffffu)), acc.z);
          acc.w = fmaf(nm, bf2f((unsigned short)(x.y >> 16)), acc.w);
        }
      }
    }
    acc.x += __shfl_xor(acc.x, 16, 64);
    acc.y += __shfl_xor(acc.y, 16, 64);
    acc.z += __shfl_xor(acc.z, 16, 64);
    acc.w += __shfl_xor(acc.w, 16, 64);
    acc.x += __shfl_xor(acc.x, 32, 64);
    acc.y += __shfl_xor(acc.y, 32, 64);
    acc.z += __shfl_xor(acc.z, 32, 64);
    acc.w += __shfl_xor(acc.w, 32, 64);
    if (quarter == 0 && w < NN) {
      const float4 b = reinterpret_cast<const float4*>(bias)[d4];
      float4 o;
      o.x = fmaxf(acc.x + b.x, 0.f);
      o.y = fmaxf(acc.y + b.y, 0.f);
      o.z = fmaxf(acc.z + b.z, 0.f);
      o.w = fmaxf(acc.w + b.w, 0.f);
      reinterpret_cast<float4*>(out)[(size_t)w * 16 + d4] = o;
    }
  }
}

extern "C" void kernel_launch(void* const* d_in, const int* in_sizes, int n_in,
                              void* d_out, int out_size, void* d_ws, size_t ws_size,
                              hipStream_t stream) {
  const float* nf = (const float*)d_in[0];
  const int* esrc = (const int*)d_in[1];
  const int* edst = (const int*)d_in[2];
  const int* etyp = (const int*)d_in[3];
  const float* enorm = (const float*)d_in[4];
  const float* W = (const float*)d_in[5];
  const float* bias = (const float*)d_in[6];
  float* out = (float*)d_out;

  char* ws = (char*)d_ws;
  unsigned short* X = (unsigned short*)ws;                 // 102,400,000 B
  unsigned short* Wt = (unsigned short*)(ws + 102400000);  //     131,072 B
  uint2* rec = (uint2*)(ws + 102531072);                   //   8,000,000 B
  int* cntT = (int*)(ws + 110531072);                      //     800,768 B
  int* offsT = (int*)(ws + 111331840);                     //     800,768 B
  int* bsum = (int*)(ws + 112132608);                      //       3,128 B
  int* bsum2 = (int*)(ws + 112135736);                     //       3,132 B
  unsigned* mask = (unsigned*)(ws + 112138868);            //     100,032 B

  k_wt<<<RR, 256, 0, stream>>>(W, Wt, mask);
  k_hist<<<NBLK, 256, 0, stream>>>(esrc, edst, etyp, cntT, mask);
  dim3 g1(NBUK, 4);
  k_gemm<<<g1, 256, 0, stream>>>(nf, Wt, mask, X);
  k_scan_a<<<NS / 256, 256, 0, stream>>>(cntT, offsT, bsum);
  k_scan_b<<<1, 1024, 0, stream>>>(bsum, bsum2);
  k_scatter<<<NBLK, 256, 0, stream>>>(esrc, edst, etyp, enorm, offsT, bsum2, rec);
  k_sortgather<<<NBUK, 1024, 0, stream>>>(bsum2, rec, X, bias, out);
}

// Round 21
// 95.445 us; speedup vs baseline: 1.4718x; 1.4718x over previous
//
#include <hip/hip_runtime.h>
#include <hip/hip_bf16.h>

// RGCN layer, MI355X (gfx950).
// R21 = R19 exact revert (best measured: 95.45us). R20 post-mortem: usage-mask store
// elision cost 49us of global-atomicOr write-through (same wall as R1) to save 9us of
// gemm writes -- dead end. This configuration: every kernel at its measured wall.
//  K0 k_wt | K1 k_gemm_hist (hist 0..255 + gemm at ~3.2TB/s write wall) | K2 k_scan_a |
//  K3 k_scan_b | K4 k_scatter | K5 k_sortgather (in-LDS bucket sort + gather fused).
//
// ws: X 102.4MB | Wt 128KB | rec 8MB | cntT 800KB | offsT 800KB | bsum | bsum2

#define NN 50000
#define EE 1000000
#define RR 16
#define NBLK 256            // binning blocks (hist/scatter)
#define EPB 3907            // ceil(EE/NBLK)
#define BSH 6               // 64 nodes per bucket
#define NBUK 782            // ceil(NN/64)
#define NS (NBUK * NBLK)    // 200192
#define SCAP 2048           // bucket LDS record capacity (mean 1279, +21 sigma)

typedef __attribute__((ext_vector_type(8))) short short8;
typedef __attribute__((ext_vector_type(4))) float f32x4;

static __device__ inline unsigned short f2bf(float f) {
  union { __hip_bfloat16 h; unsigned short u; } cv;
  cv.h = __float2bfloat16(f);
  return cv.u;
}
static __device__ inline float bf2f(unsigned short u) {
  union { unsigned i; float f; } cv;
  cv.i = ((unsigned)u) << 16;
  return cv.f;
}

// ---------------- K0: W[r][k][o] fp32 -> Wt[r][o][k] bf16 (one-time) ----------------
__global__ __launch_bounds__(256) void k_wt(const float* __restrict__ W,
                                            unsigned short* __restrict__ Wt) {
  __shared__ __align__(16) unsigned short Wl[64][72];
  const int r = blockIdx.x, tid = threadIdx.x;
  for (int i = tid; i < 4096; i += 256) Wl[i & 63][i >> 6] = f2bf(W[(r << 12) + i]);
  __syncthreads();
  const int o = tid >> 2, kc = (tid & 3) << 4;
  const short8 v0 = *reinterpret_cast<const short8*>(&Wl[o][kc]);
  const short8 v1 = *reinterpret_cast<const short8*>(&Wl[o][kc + 8]);
  unsigned short* dst = Wt + (r << 12) + (o << 6) + kc;
  *reinterpret_cast<short8*>(dst) = v0;
  *reinterpret_cast<short8*>(dst + 8) = v1;
}

// ---------------- K1: fused edge-histogram + dense transform ----------------
__global__ __launch_bounds__(256) void k_gemm_hist(const float* __restrict__ nf,
                                                   const unsigned short* __restrict__ Wt,
                                                   const int* __restrict__ edst,
                                                   unsigned short* __restrict__ X,
                                                   int* __restrict__ cntT) {
  __shared__ __align__(16) char smem[4 * 64 * 72 * 2];  // 36,864 B union
  const int bid = blockIdx.x, tid = threadIdx.x;
  if (bid < NBLK) {
    // ---- histogram path ----
    int* cnt = reinterpret_cast<int*>(smem);
    for (int i = tid; i < NBUK; i += 256) cnt[i] = 0;
    __syncthreads();
    const int e0 = bid * EPB, e1 = min(EE, e0 + EPB);
    for (int e = e0 + tid; e < e1; e += 256) atomicAdd(&cnt[edst[e] >> BSH], 1);
    __syncthreads();
    for (int i = tid; i < NBUK; i += 256) cntT[i * NBLK + bid] = cnt[i];
    return;
  }
  // ---- gemm path ----
  auto Wl = reinterpret_cast<unsigned short(*)[64][72]>(smem);
  const int g = bid - NBLK;
  const int bx = g >> 2, r0 = (g & 3) << 2;
  const int lane = tid & 63, wv = tid >> 6;
  const int lr = lane & 15, lg = lane >> 4;
  const int node = (bx << 6) + (wv << 4) + lr;
  #pragma unroll
  for (int rr = 0; rr < 4; ++rr) {
    const unsigned short* src = Wt + (((size_t)(r0 + rr)) << 12) + (tid << 4);
    const short8 v0 = *reinterpret_cast<const short8*>(src);
    const short8 v1 = *reinterpret_cast<const short8*>(src + 8);
    unsigned short* dst = &Wl[rr][tid >> 2][(tid & 3) << 4];
    *reinterpret_cast<short8*>(dst) = v0;
    *reinterpret_cast<short8*>(dst + 8) = v1;
  }
  short8 bf0, bf1;
  if (node < NN) {
    const float* ap = nf + (size_t)node * 64 + lg * 8;
    float4 v0 = *reinterpret_cast<const float4*>(ap);
    float4 v1 = *reinterpret_cast<const float4*>(ap + 4);
    float4 v2 = *reinterpret_cast<const float4*>(ap + 32);
    float4 v3 = *reinterpret_cast<const float4*>(ap + 36);
    bf0 = short8{(short)f2bf(v0.x), (short)f2bf(v0.y), (short)f2bf(v0.z), (short)f2bf(v0.w),
                 (short)f2bf(v1.x), (short)f2bf(v1.y), (short)f2bf(v1.z), (short)f2bf(v1.w)};
    bf1 = short8{(short)f2bf(v2.x), (short)f2bf(v2.y), (short)f2bf(v2.z), (short)f2bf(v2.w),
                 (short)f2bf(v3.x), (short)f2bf(v3.y), (short)f2bf(v3.z), (short)f2bf(v3.w)};
  } else {
    bf0 = short8{0, 0, 0, 0, 0, 0, 0, 0};
    bf1 = bf0;
  }
  __syncthreads();
  #pragma unroll
  for (int rr = 0; rr < 4; ++rr) {
    const int r = r0 + rr;
    short8 a[8];
    #pragma unroll
    for (int c = 0; c < 4; ++c) {
      a[2 * c] = *reinterpret_cast<const short8*>(&Wl[rr][(c << 4) + lr][lg << 3]);
      a[2 * c + 1] = *reinterpret_cast<const short8*>(&Wl[rr][(c << 4) + lr][32 + (lg << 3)]);
    }
    f32x4 acc[4];
    #pragma unroll
    for (int c = 0; c < 4; ++c) {
      acc[c] = f32x4{0.f, 0.f, 0.f, 0.f};
      acc[c] = __builtin_amdgcn_mfma_f32_16x16x32_bf16(a[2 * c], bf0, acc[c], 0, 0, 0);
      acc[c] = __builtin_amdgcn_mfma_f32_16x16x32_bf16(a[2 * c + 1], bf1, acc[c], 0, 0, 0);
    }
    if (node < NN) {
      #pragma unroll
      for (int c = 0; c < 4; ++c) {
        uint2 p;
        p.x = (unsigned)f2bf(acc[c][0]) | ((unsigned)f2bf(acc[c][1]) << 16);
        p.y = (unsigned)f2bf(acc[c][2]) | ((unsigned)f2bf(acc[c][3]) << 16);
        *reinterpret_cast<uint2*>(&X[((size_t)r * NN + node) * 64 + (c << 4) + (lg << 2)]) = p;
      }
    }
  }
}

// ---------------- K2: per-bucket scan of per-block counts ----------------
__global__ __launch_bounds__(256) void k_scan_a(const int* __restrict__ cntT,
                                                int* __restrict__ offsT,
                                                int* __restrict__ bsum) {
  __shared__ int s[256];
  const int t = threadIdx.x;
  const int i = blockIdx.x * 256 + t;
  const int v = cntT[i];
  s[t] = v;
  __syncthreads();
  #pragma unroll
  for (int off = 1; off < 256; off <<= 1) {
    const int x = (t >= off) ? s[t - off] : 0;
    __syncthreads();
    s[t] += x;
    __syncthreads();
  }
  offsT[i] = s[t] - v;
  if (t == 255) bsum[blockIdx.x] = s[255];
}

// ---------------- K3: scan bucket totals -> global bucket starts ----------------
__global__ __launch_bounds__(1024) void k_scan_b(const int* __restrict__ bsum,
                                                 int* __restrict__ bsum2) {
  __shared__ int s[1024];
  const int t = threadIdx.x;
  const int v = (t < NBUK) ? bsum[t] : 0;
  s[t] = v;
  __syncthreads();
  #pragma unroll
  for (int off = 1; off < 1024; off <<= 1) {
    const int x = (t >= off) ? s[t - off] : 0;
    __syncthreads();
    s[t] += x;
    __syncthreads();
  }
  if (t < NBUK) bsum2[t] = s[t] - v;
  if (t == NBUK) bsum2[NBUK] = EE;
}

// ---------------- K4: private counting-sort scatter ----------------
__global__ __launch_bounds__(256) void k_scatter(const int* __restrict__ esrc,
                                                 const int* __restrict__ edst,
                                                 const int* __restrict__ etyp,
                                                 const float* __restrict__ enorm,
                                                 const int* __restrict__ offsT,
                                                 const int* __restrict__ bsum2,
                                                 uint2* __restrict__ rec) {
  __shared__ int cur[NBUK];
  const int bl = blockIdx.x, tid = threadIdx.x;
  for (int i = tid; i < NBUK; i += 256) cur[i] = offsT[i * NBLK + bl] + bsum2[i];
  __syncthreads();
  const int e0 = bl * EPB, e1 = min(EE, e0 + EPB);
  for (int e = e0 + tid; e < e1; e += 256) {
    const int d = edst[e];
    const int pos = atomicAdd(&cur[d >> BSH], 1);
    // pack: (typ*NN+src)<<6 | dstlow  (r.x>>6 == X row id, typ-major layout)
    rec[pos] = make_uint2(((unsigned)(etyp[e] * NN + esrc[e]) << 6) | (unsigned)(d & 63),
                          __float_as_uint(enorm[e]));
  }
}

// ---------------- K5: fused in-LDS node sort + gather + bias + relu ----------------
// Block = 1024 thr / 16 waves per bucket. Sort bucket records into sbuf2 (LDS
// counting sort by dst&63); wave wv gathers nodes wv*4..wv*4+3 straight from LDS.
__global__ __launch_bounds__(1024) void k_sortgather(const int* __restrict__ bsum2,
                                                     const uint2* __restrict__ rec,
                                                     const unsigned short* __restrict__ X,
                                                     const float* __restrict__ bias,
                                                     float* __restrict__ out) {
  __shared__ uint2 sbuf[SCAP];   // 16 KB raw
  __shared__ uint2 sbuf2[SCAP];  // 16 KB node-sorted
  __shared__ int cnt[64], cur[64], nstart[65];
  const int bu = blockIdx.x, tid = threadIdx.x;
  const int s = bsum2[bu];
  const int e = bsum2[bu + 1];
  const int n = e - s;
  const int lane = tid & 63, wv = tid >> 6;
  const int quarter = lane >> 4, d4 = lane & 15;
  if (tid < 64) cnt[tid] = 0;
  __syncthreads();
  const bool sorted = (n <= SCAP);
  if (sorted) {
    for (int i = tid; i < n; i += 1024) {
      const uint2 r = rec[s + i];
      sbuf[i] = r;
      atomicAdd(&cnt[r.x & 63u], 1);  // native ds_add_u32
    }
    __syncthreads();
    if (tid < 64) {  // wave-0 shfl exclusive scan of 64 bins
      const int v = cnt[tid];
      int x = v;
      #pragma unroll
      for (int off = 1; off < 64; off <<= 1) {
        const int t = __shfl_up(x, off, 64);
        if (tid >= off) x += t;
      }
      cur[tid] = x - v;
      nstart[tid] = x - v;
      if (tid == 63) nstart[64] = n;
    }
    __syncthreads();
    for (int i = tid; i < n; i += 1024) {
      const uint2 r = sbuf[i];
      const int pos = atomicAdd(&cur[r.x & 63u], 1);
      sbuf2[pos] = r;
    }
    __syncthreads();
  }
  // gather: wave wv owns local nodes wv*4 .. wv*4+3 (no barriers below)
  #pragma unroll
  for (int k = 0; k < 4; ++k) {
    const int nl = (wv << 2) + k;
    const int w = (bu << BSH) + nl;
    float4 acc = {0.f, 0.f, 0.f, 0.f};
    if (sorted) {
      const int jb = nstart[nl], je = nstart[nl + 1];
      for (int base = jb; base < je; base += 64) {
        const int deg = min(64, je - base);
        unsigned rxs = 0;
        float rns = 0.f;
        if (lane < deg) {
          const uint2 r = sbuf2[base + lane];
          rxs = r.x >> 6;
          rns = __uint_as_float(r.y);
        }
        int u = 0;
        for (; u + 16 <= deg; u += 16) {  // 16 edges per body, 4 independent X loads
          unsigned row[4];
          float nm[4];
          uint2 xv[4];
          #pragma unroll
          for (int q = 0; q < 4; ++q) {
            const int i = u + 4 * q + quarter;
            row[q] = (unsigned)__shfl((int)rxs, i, 64);
            nm[q] = __shfl(rns, i, 64);
          }
          #pragma unroll
          for (int q = 0; q < 4; ++q)
            xv[q] = *reinterpret_cast<const uint2*>(X + (size_t)row[q] * 64 + (d4 << 2));
          #pragma unroll
          for (int q = 0; q < 4; ++q) {
            acc.x = fmaf(nm[q], bf2f((unsigned short)(xv[q].x & 0xffffu)), acc.x);
            acc.y = fmaf(nm[q], bf2f((unsigned short)(xv[q].x >> 16)), acc.y);
            acc.z = fmaf(nm[q], bf2f((unsigned short)(xv[q].y & 0xffffu)), acc.z);
            acc.w = fmaf(nm[q], bf2f((unsigned short)(xv[q].y >> 16)), acc.w);
          }
        }
        for (; u + 8 <= deg; u += 8) {
          const int i0 = u + quarter, i1 = u + 4 + quarter;
          const unsigned row0 = (unsigned)__shfl((int)rxs, i0, 64);
          const float n0 = __shfl(rns, i0, 64);
          const unsigned row1 = (unsigned)__shfl((int)rxs, i1, 64);
          const float n1 = __shfl(rns, i1, 64);
          const uint2 x0 = *reinterpret_cast<const uint2*>(X + (size_t)row0 * 64 + (d4 << 2));
          const uint2 x1 = *reinterpret_cast<const uint2*>(X + (size_t)row1 * 64 + (d4 << 2));
          acc.x = fmaf(n0, bf2f((unsigned short)(x0.x & 0xffffu)), acc.x);
          acc.y = fmaf(n0, bf2f((unsigned short)(x0.x >> 16)), acc.y);
          acc.z = fmaf(n0, bf2f((unsigned short)(x0.y & 0xffffu)), acc.z);
          acc.w = fmaf(n0, bf2f((unsigned short)(x0.y >> 16)), acc.w);
          acc.x = fmaf(n1, bf2f((unsigned short)(x1.x & 0xffffu)), acc.x);
          acc.y = fmaf(n1, bf2f((unsigned short)(x1.x >> 16)), acc.y);
          acc.z = fmaf(n1, bf2f((unsigned short)(x1.y & 0xffffu)), acc.z);
          acc.w = fmaf(n1, bf2f((unsigned short)(x1.y >> 16)), acc.w);
        }
        for (; u < deg; u += 4) {
          const int i = u + quarter;
          const int ic = min(i, deg - 1);
          const unsigned row = (unsigned)__shfl((int)rxs, ic, 64);
          float nm = __shfl(rns, ic, 64);
          nm = (i < deg) ? nm : 0.f;
          const uint2 x = *reinterpret_cast<const uint2*>(X + (size_t)row * 64 + (d4 << 2));
          acc.x = fmaf(nm, bf2f((unsigned short)(x.x & 0xffffu)), acc.x);
          acc.y = fmaf(nm, bf2f((unsigned short)(x.x >> 16)), acc.y);
          acc.z = fmaf(nm, bf2f((unsigned short)(x.y & 0xffffu)), acc.z);
          acc.w = fmaf(nm, bf2f((unsigned short)(x.y >> 16)), acc.w);
        }
      }
    } else if (quarter == 0) {
      // ~impossible oversized bucket: filter-scan global rec
      const unsigned dl = (unsigned)nl;
      for (int j = s; j < e; ++j) {
        const uint2 r = rec[j];
        if ((r.x & 63u) == dl) {
          const float nm = __uint_as_float(r.y);
          const uint2 x =
              *reinterpret_cast<const uint2*>(X + (size_t)(r.x >> 6) * 64 + (d4 << 2));
          acc.x = fmaf(nm, bf2f((unsigned short)(x.x & 0xffffu)), acc.x);
          acc.y = fmaf(nm, bf2f((unsigned short)(x.x >> 16)), acc.y);
          acc.z = fmaf(nm, bf2f((unsigned short)(x.y & 0xffffu)), acc.z);
          acc.w = fmaf(nm, bf2f((unsigned short)(x.y >> 16)), acc.w);
        }
      }
    }
    acc.x += __shfl_xor(acc.x, 16, 64);
    acc.y += __shfl_xor(acc.y, 16, 64);
    acc.z += __shfl_xor(acc.z, 16, 64);
    acc.w += __shfl_xor(acc.w, 16, 64);
    acc.x += __shfl_xor(acc.x, 32, 64);
    acc.y += __shfl_xor(acc.y, 32, 64);
    acc.z += __shfl_xor(acc.z, 32, 64);
    acc.w += __shfl_xor(acc.w, 32, 64);
    if (quarter == 0 && w < NN) {
      const float4 b = reinterpret_cast<const float4*>(bias)[d4];
      float4 o;
      o.x = fmaxf(acc.x + b.x, 0.f);
      o.y = fmaxf(acc.y + b.y, 0.f);
      o.z = fmaxf(acc.z + b.z, 0.f);
      o.w = fmaxf(acc.w + b.w, 0.f);
      reinterpret_cast<float4*>(out)[(size_t)w * 16 + d4] = o;
    }
  }
}

extern "C" void kernel_launch(void* const* d_in, const int* in_sizes, int n_in,
                              void* d_out, int out_size, void* d_ws, size_t ws_size,
                              hipStream_t stream) {
  const float* nf = (const float*)d_in[0];
  const int* esrc = (const int*)d_in[1];
  const int* edst = (const int*)d_in[2];
  const int* etyp = (const int*)d_in[3];
  const float* enorm = (const float*)d_in[4];
  const float* W = (const float*)d_in[5];
  const float* bias = (const float*)d_in[6];
  float* out = (float*)d_out;

  char* ws = (char*)d_ws;
  unsigned short* X = (unsigned short*)ws;                 // 102,400,000 B
  unsigned short* Wt = (unsigned short*)(ws + 102400000);  //     131,072 B
  uint2* rec = (uint2*)(ws + 102531072);                   //   8,000,000 B
  int* cntT = (int*)(ws + 110531072);                      //     800,768 B
  int* offsT = (int*)(ws + 111331840);                     //     800,768 B
  int* bsum = (int*)(ws + 112132608);                      //       3,128 B
  int* bsum2 = (int*)(ws + 112135736);                     //       3,132 B

  k_wt<<<RR, 256, 0, stream>>>(W, Wt);
  k_gemm_hist<<<NBLK + NBUK * 4, 256, 0, stream>>>(nf, Wt, edst, X, cntT);
  k_scan_a<<<NS / 256, 256, 0, stream>>>(cntT, offsT, bsum);
  k_scan_b<<<1, 1024, 0, stream>>>(bsum, bsum2);
  k_scatter<<<NBLK, 256, 0, stream>>>(esrc, edst, etyp, enorm, offsT, bsum2, rec);
  k_sortgather<<<NBUK, 1024, 0, stream>>>(bsum2, rec, X, bias, out);
}